// Round 4
// baseline (68.616 us; speedup 1.0000x reference)
//
#include <hip/hip_runtime.h>

// FractalEmbedding: tokens -> Julia features (16 fp32) -> 16x2048 projection.
// Output 4*8192*2048 fp32 = 268 MB => store-bandwidth-bound (~38 us at the
// 7 TB/s the harness's own fillBuffer achieves).
//
// R4 = R3 with the nontemporal store fixed: use a native ext_vector float4
// (__builtin_nontemporal_store rejects HIP_vector_type<float,4>).

constexpr int TOKENS = 4 * 8192;   // 32768
constexpr int EMBED  = 2048;
constexpr int NF     = 16;         // 2 * STEPS
constexpr int STEPS  = 8;
constexpr int TB     = 64;         // tokens per block

typedef float f32x4 __attribute__((ext_vector_type(4)));

// ---------------- kernel 1: Julia features ----------------
__global__ __launch_bounds__(256)
void feats_kernel(const int* __restrict__ tok,
                  const float* __restrict__ crt,
                  const float* __restrict__ cit,
                  float* __restrict__ feats)   // [TOKENS][NF]
{
    const int t = blockIdx.x * 256 + threadIdx.x;
    const int id = tok[t];
    const float cr = crt[id];
    const float ci = cit[id];
    float f[NF];
    float zr = 0.0f, zi = 0.0f;
    #pragma unroll
    for (int st = 0; st < STEPS; ++st) {
        const float nzr = zr * zr - zi * zi + cr;
        const float nzi = 2.0f * zr * zi + ci;
        zr = nzr; zi = nzi;
        f[2 * st]     = zr;
        f[2 * st + 1] = zi;
    }
    f32x4* fo = reinterpret_cast<f32x4*>(feats + (size_t)t * NF);
    #pragma unroll
    for (int j = 0; j < 4; ++j) {
        f32x4 v = { f[4 * j], f[4 * j + 1], f[4 * j + 2], f[4 * j + 3] };
        fo[j] = v;
    }
}

// ---------------- kernel 2: projection, contiguous-region blocks ----------------
__global__ __launch_bounds__(512)
void proj_kernel(const float* __restrict__ feats,  // [TOKENS][NF]
                 const float* __restrict__ W,      // [EMBED][NF]
                 const float* __restrict__ scale_p,
                 float* __restrict__ out)          // [TOKENS][EMBED]
{
    const int tid = threadIdx.x;
    const int d0  = tid * 4;                 // 4 consecutive dims per thread
    const float s = scale_p[0];

    // 4 rows of W (64 floats, contiguous) -> registers, scale folded in.
    float w[4][NF];
    {
        const f32x4* W4 = reinterpret_cast<const f32x4*>(W + (size_t)d0 * NF);
        #pragma unroll
        for (int r = 0; r < 4; ++r) {
            #pragma unroll
            for (int k = 0; k < 4; ++k) {
                f32x4 v = W4[r * 4 + k];
                w[r][k * 4 + 0] = v.x * s;
                w[r][k * 4 + 1] = v.y * s;
                w[r][k * 4 + 2] = v.z * s;
                w[r][k * 4 + 3] = v.w * s;
            }
        }
    }

    const int tok0 = blockIdx.x * TB;
    const float* fbase = feats + (size_t)tok0 * NF;
    float* __restrict__ obase = out + (size_t)tok0 * EMBED + d0;

    #pragma unroll 2
    for (int i = 0; i < TB; ++i) {
        // Wave-uniform feats address (scalar-load candidate, cache-resident).
        float f[NF];
        {
            const f32x4* fp = reinterpret_cast<const f32x4*>(fbase + i * NF);
            #pragma unroll
            for (int k = 0; k < 4; ++k) {
                f32x4 v = fp[k];
                f[k * 4 + 0] = v.x;
                f[k * 4 + 1] = v.y;
                f[k * 4 + 2] = v.z;
                f[k * 4 + 3] = v.w;
            }
        }
        float acc[4];
        #pragma unroll
        for (int r = 0; r < 4; ++r) {
            float a = 0.0f;
            #pragma unroll
            for (int k = 0; k < NF; ++k)
                a = fmaf(f[k], w[r][k], a);
            acc[r] = a;
        }
        f32x4 o = { acc[0], acc[1], acc[2], acc[3] };
        __builtin_nontemporal_store(o, reinterpret_cast<f32x4*>(obase + (size_t)i * EMBED));
    }
}

// ---------------- fallback (fused, known-good R1) if ws too small ----------------
__global__ __launch_bounds__(512)
void fused_kernel(const int* __restrict__ tok,
                  const float* __restrict__ crt,
                  const float* __restrict__ cit,
                  const float* __restrict__ W,
                  const float* __restrict__ scale_p,
                  float* __restrict__ out)
{
    const int tid = threadIdx.x;
    const float s = scale_p[0];
    float w[4][NF];
    {
        const float4* W4 = reinterpret_cast<const float4*>(W + (size_t)tid * 4 * NF);
        #pragma unroll
        for (int r = 0; r < 4; ++r)
            #pragma unroll
            for (int k = 0; k < 4; ++k) {
                float4 v = W4[r * 4 + k];
                w[r][k * 4 + 0] = v.x; w[r][k * 4 + 1] = v.y;
                w[r][k * 4 + 2] = v.z; w[r][k * 4 + 3] = v.w;
            }
    }
    __shared__ float feats[64][NF];
    const int tok0 = blockIdx.x * 64;
    if (tid < 64) {
        const int t = tok[tok0 + tid];
        const float cr = crt[t], ci = cit[t];
        float zr = 0.0f, zi = 0.0f;
        #pragma unroll
        for (int st = 0; st < STEPS; ++st) {
            const float nzr = zr * zr - zi * zi + cr;
            const float nzi = 2.0f * zr * zi + ci;
            zr = nzr; zi = nzi;
            feats[tid][2 * st] = zr; feats[tid][2 * st + 1] = zi;
        }
    }
    __syncthreads();
    float4* out4 = reinterpret_cast<float4*>(out);
    for (int i = 0; i < 64; ++i) {
        float f[NF];
        const float4* fp = reinterpret_cast<const float4*>(feats[i]);
        #pragma unroll
        for (int k = 0; k < 4; ++k) {
            float4 v = fp[k];
            f[k * 4 + 0] = v.x; f[k * 4 + 1] = v.y;
            f[k * 4 + 2] = v.z; f[k * 4 + 3] = v.w;
        }
        float acc[4];
        #pragma unroll
        for (int r = 0; r < 4; ++r) {
            float a = 0.0f;
            #pragma unroll
            for (int k = 0; k < NF; ++k) a = fmaf(f[k], w[r][k], a);
            acc[r] = a * s;
        }
        out4[(size_t)(tok0 + i) * (EMBED / 4) + tid] =
            make_float4(acc[0], acc[1], acc[2], acc[3]);
    }
}

extern "C" void kernel_launch(void* const* d_in, const int* in_sizes, int n_in,
                              void* d_out, int out_size, void* d_ws, size_t ws_size,
                              hipStream_t stream) {
    const int*   tok   = (const int*)d_in[0];
    const float* crt   = (const float*)d_in[1];
    const float* cit   = (const float*)d_in[2];
    const float* W     = (const float*)d_in[3];
    const float* scale = (const float*)d_in[4];
    float*       out   = (float*)d_out;

    const size_t feats_bytes = (size_t)TOKENS * NF * sizeof(float);
    if (ws_size >= feats_bytes) {
        float* feats = (float*)d_ws;
        feats_kernel<<<TOKENS / 256, 256, 0, stream>>>(tok, crt, cit, feats);
        proj_kernel<<<TOKENS / TB, 512, 0, stream>>>(feats, W, scale, out);
    } else {
        fused_kernel<<<TOKENS / 64, 512, 0, stream>>>(tok, crt, cit, W, scale, out);
    }
}

// Round 5
// 58.616 us; speedup vs baseline: 1.1706x; 1.1706x over previous
//
#include <hip/hip_runtime.h>

// FractalEmbedding: tokens -> Julia features (16 fp32) -> 16x2048 projection.
// Output 268 MB fp32 => store-bandwidth-bound (~38 us at the 7 TB/s the
// harness's own fillBuffer sustains).
//
// R5 = R2's winning shape (256 thr, 2 dims/thread, 4 d-chunks x 512 token
// groups) + packed v_pk_fma_f32 accumulation (halves FMA issue) + manual
// 2-token ILP unroll + __launch_bounds__(256,5) for >=20 waves/CU.

constexpr int TOKENS = 4 * 8192;   // 32768
constexpr int EMBED  = 2048;
constexpr int NF     = 16;         // 2 * STEPS
constexpr int STEPS  = 8;
constexpr int TB     = 64;         // tokens per block

typedef float f32x2 __attribute__((ext_vector_type(2)));
typedef float f32x4 __attribute__((ext_vector_type(4)));

// ---------------- kernel 1: Julia features ----------------
__global__ __launch_bounds__(256)
void feats_kernel(const int* __restrict__ tok,
                  const float* __restrict__ crt,
                  const float* __restrict__ cit,
                  float* __restrict__ feats)   // [TOKENS][NF]
{
    const int t = blockIdx.x * 256 + threadIdx.x;
    const int id = tok[t];
    const float cr = crt[id];
    const float ci = cit[id];
    float f[NF];
    float zr = 0.0f, zi = 0.0f;
    #pragma unroll
    for (int st = 0; st < STEPS; ++st) {
        const float nzr = zr * zr - zi * zi + cr;
        const float nzi = 2.0f * zr * zi + ci;
        zr = nzr; zi = nzi;
        f[2 * st]     = zr;
        f[2 * st + 1] = zi;
    }
    f32x4* fo = reinterpret_cast<f32x4*>(feats + (size_t)t * NF);
    #pragma unroll
    for (int j = 0; j < 4; ++j) {
        f32x4 v = { f[4 * j], f[4 * j + 1], f[4 * j + 2], f[4 * j + 3] };
        fo[j] = v;
    }
}

// ---------------- kernel 2: projection ----------------
// grid: 4 d-chunks (512 dims) minor x 512 token-groups (64 tokens) major.
__global__ __launch_bounds__(256, 5)
void proj_kernel(const float* __restrict__ feats,  // [TOKENS][NF]
                 const float* __restrict__ W,      // [EMBED][NF]
                 const float* __restrict__ scale_p,
                 float* __restrict__ out)          // [TOKENS][EMBED]
{
    const int tid  = threadIdx.x;
    const int dblk = blockIdx.x & 3;
    const int tblk = blockIdx.x >> 2;
    const int d0   = dblk * 512 + tid * 2;   // this thread's dim pair
    const float s  = scale_p[0];

    // w2[k] = { W[d0][k], W[d0+1][k] } * s  -> 16 packed pairs (32 VGPR).
    f32x2 w2[NF];
    {
        const f32x4* W4 = reinterpret_cast<const f32x4*>(W + (size_t)d0 * NF);
        #pragma unroll
        for (int k = 0; k < 4; ++k) {
            f32x4 a = W4[k];       // row d0, feats 4k..4k+3
            f32x4 b = W4[4 + k];   // row d0+1
            w2[4 * k + 0] = (f32x2){ a.x * s, b.x * s };
            w2[4 * k + 1] = (f32x2){ a.y * s, b.y * s };
            w2[4 * k + 2] = (f32x2){ a.z * s, b.z * s };
            w2[4 * k + 3] = (f32x2){ a.w * s, b.w * s };
        }
    }

    const float* fbase = feats + (size_t)tblk * TB * NF;
    f32x2* __restrict__ out2 = reinterpret_cast<f32x2*>(out);
    const int obase = dblk * 256 + tid;      // float2 units within a row
    const size_t orow0 = (size_t)tblk * TB * (EMBED / 2) + obase;

    for (int i = 0; i < TB; i += 2) {
        // Two independent token chains in flight (wave-uniform addresses).
        float fa[NF], fb[NF];
        {
            const f32x4* fpa = reinterpret_cast<const f32x4*>(fbase + i * NF);
            const f32x4* fpb = reinterpret_cast<const f32x4*>(fbase + (i + 1) * NF);
            #pragma unroll
            for (int k = 0; k < 4; ++k) {
                f32x4 va = fpa[k], vb = fpb[k];
                fa[4 * k + 0] = va.x; fa[4 * k + 1] = va.y;
                fa[4 * k + 2] = va.z; fa[4 * k + 3] = va.w;
                fb[4 * k + 0] = vb.x; fb[4 * k + 1] = vb.y;
                fb[4 * k + 2] = vb.z; fb[4 * k + 3] = vb.w;
            }
        }
        f32x2 accA = (f32x2){0.0f, 0.0f};
        f32x2 accB = (f32x2){0.0f, 0.0f};
        #pragma unroll
        for (int k = 0; k < NF; ++k) {
            accA += (f32x2){ fa[k], fa[k] } * w2[k];   // v_pk_fma_f32
            accB += (f32x2){ fb[k], fb[k] } * w2[k];
        }
        out2[orow0 + (size_t)i       * (EMBED / 2)] = accA;
        out2[orow0 + (size_t)(i + 1) * (EMBED / 2)] = accB;
    }
}

// ---------------- fallback (fused) if ws too small ----------------
__global__ __launch_bounds__(512)
void fused_kernel(const int* __restrict__ tok,
                  const float* __restrict__ crt,
                  const float* __restrict__ cit,
                  const float* __restrict__ W,
                  const float* __restrict__ scale_p,
                  float* __restrict__ out)
{
    const int tid = threadIdx.x;
    const float s = scale_p[0];
    float w[4][NF];
    {
        const float4* W4 = reinterpret_cast<const float4*>(W + (size_t)tid * 4 * NF);
        #pragma unroll
        for (int r = 0; r < 4; ++r)
            #pragma unroll
            for (int k = 0; k < 4; ++k) {
                float4 v = W4[r * 4 + k];
                w[r][k * 4 + 0] = v.x; w[r][k * 4 + 1] = v.y;
                w[r][k * 4 + 2] = v.z; w[r][k * 4 + 3] = v.w;
            }
    }
    __shared__ float feats[64][NF];
    const int tok0 = blockIdx.x * 64;
    if (tid < 64) {
        const int t = tok[tok0 + tid];
        const float cr = crt[t], ci = cit[t];
        float zr = 0.0f, zi = 0.0f;
        #pragma unroll
        for (int st = 0; st < STEPS; ++st) {
            const float nzr = zr * zr - zi * zi + cr;
            const float nzi = 2.0f * zr * zi + ci;
            zr = nzr; zi = nzi;
            feats[tid][2 * st] = zr; feats[tid][2 * st + 1] = zi;
        }
    }
    __syncthreads();
    float4* out4 = reinterpret_cast<float4*>(out);
    for (int i = 0; i < 64; ++i) {
        float f[NF];
        const float4* fp = reinterpret_cast<const float4*>(feats[i]);
        #pragma unroll
        for (int k = 0; k < 4; ++k) {
            float4 v = fp[k];
            f[k * 4 + 0] = v.x; f[k * 4 + 1] = v.y;
            f[k * 4 + 2] = v.z; f[k * 4 + 3] = v.w;
        }
        float acc[4];
        #pragma unroll
        for (int r = 0; r < 4; ++r) {
            float a = 0.0f;
            #pragma unroll
            for (int k = 0; k < NF; ++k) a = fmaf(f[k], w[r][k], a);
            acc[r] = a * s;
        }
        out4[(size_t)(tok0 + i) * (EMBED / 4) + tid] =
            make_float4(acc[0], acc[1], acc[2], acc[3]);
    }
}

extern "C" void kernel_launch(void* const* d_in, const int* in_sizes, int n_in,
                              void* d_out, int out_size, void* d_ws, size_t ws_size,
                              hipStream_t stream) {
    const int*   tok   = (const int*)d_in[0];
    const float* crt   = (const float*)d_in[1];
    const float* cit   = (const float*)d_in[2];
    const float* W     = (const float*)d_in[3];
    const float* scale = (const float*)d_in[4];
    float*       out   = (float*)d_out;

    const size_t feats_bytes = (size_t)TOKENS * NF * sizeof(float);
    if (ws_size >= feats_bytes) {
        float* feats = (float*)d_ws;
        feats_kernel<<<TOKENS / 256, 256, 0, stream>>>(tok, crt, cit, feats);
        proj_kernel<<<4 * (TOKENS / TB), 256, 0, stream>>>(feats, W, scale, out);
    } else {
        fused_kernel<<<TOKENS / 64, 512, 0, stream>>>(tok, crt, cit, W, scale, out);
    }
}